// Round 12
// baseline (294.937 us; speedup 1.0000x reference)
//
#include <hip/hip_runtime.h>

#define N_NODES 100000
#define N_EDGES 1600000
#define D 128
#define G 64                       // nodes per bucket (dst >> 6)
#define NB 1563                    // ceil(N_NODES / G)
#define NB_PAD 1568
#define CAP 1536                   // bucket capacity: mean 1024, +16 sigma
#define EPT 16                     // edges per thread in bin_count

typedef __attribute__((ext_vector_type(8))) short bf16x8;
typedef __attribute__((ext_vector_type(4))) float f32x4;

__device__ inline float bf2f(unsigned short u) {
    return __uint_as_float(((unsigned int)u) << 16);
}
__device__ inline unsigned short f2bf(float f) {  // round-to-nearest-even
    unsigned int u = __float_as_uint(f);
    unsigned int r = u + 0x7FFF + ((u >> 16) & 1);
    return (unsigned short)(r >> 16);
}

__device__ inline int wave_incl_scan(int v, int lane) {
    #pragma unroll
    for (int off = 1; off < 64; off <<= 1) {
        int y = __shfl_up(v, off);
        if (lane >= off) v += y;
    }
    return v;
}

// ---- K1: bin edges by dst>>6 (packed src | dlocal<<17) + global per-node deg count.
__global__ __launch_bounds__(256) void bin_count(const int* __restrict__ ei,
                                                 int* __restrict__ deg,
                                                 int* __restrict__ gcursor,
                                                 unsigned int* __restrict__ bins) {
    __shared__ int hist[NB];
    __shared__ int base[NB];
    const int tid = threadIdx.x;
    for (int i = tid; i < NB; i += 256) hist[i] = 0;
    __syncthreads();

    const long long e0 = (long long)blockIdx.x * (256 * EPT) + (long long)tid * EPT;
    const bool active = (e0 < N_EDGES);   // tails are EPT-aligned -> all-or-nothing
    unsigned int packed[EPT]; int bkt[EPT]; int rnk[EPT];
    if (active) {
        const int4* s4 = (const int4*)(ei + e0);
        const int4* d4 = (const int4*)(ei + N_EDGES + e0);
        #pragma unroll
        for (int q = 0; q < EPT / 4; ++q) {
            int4 s = s4[q], d = d4[q];
            int j = q * 4;
            bkt[j+0] = d.x >> 6; packed[j+0] = (unsigned)s.x | ((unsigned)(d.x & 63) << 17);
            bkt[j+1] = d.y >> 6; packed[j+1] = (unsigned)s.y | ((unsigned)(d.y & 63) << 17);
            bkt[j+2] = d.z >> 6; packed[j+2] = (unsigned)s.z | ((unsigned)(d.z & 63) << 17);
            bkt[j+3] = d.w >> 6; packed[j+3] = (unsigned)s.w | ((unsigned)(d.w & 63) << 17);
            atomicAdd(&deg[d.x], 1);
            atomicAdd(&deg[d.y], 1);
            atomicAdd(&deg[d.z], 1);
            atomicAdd(&deg[d.w], 1);
        }
        #pragma unroll
        for (int j = 0; j < EPT; ++j) rnk[j] = atomicAdd(&hist[bkt[j]], 1);
    }
    __syncthreads();
    for (int i = tid; i < NB; i += 256) {
        int c = hist[i];
        base[i] = c ? atomicAdd(&gcursor[i], c) : 0;
    }
    __syncthreads();
    if (active) {
        #pragma unroll
        for (int j = 0; j < EPT; ++j) {
            int pos = base[bkt[j]] + rnk[j];
            if (pos < CAP) bins[(size_t)bkt[j] * CAP + pos] = packed[j];
        }
    }
}

// ---- K2: h'[r] = rsqrt(deg[r]+1) * (x[r] @ W) via bf16 MFMA, stored bf16.
// 512 threads = 8 waves; 128 rows/block. W transposed+XOR-swizzled in LDS.
__global__ __launch_bounds__(512) void gemm_h_mfma(
        const float* __restrict__ x, const float* __restrict__ W,
        const int* __restrict__ deg, unsigned short* __restrict__ h) {
    __shared__ unsigned short wt[D * D];  // 32 KB
    const int tid  = threadIdx.x;
    const int lane = tid & 63;
    const int wv   = tid >> 6;
    const int rb   = blockIdx.x * 128 + wv * 16;

    int arow = rb + (lane & 15);
    if (arow >= N_NODES) arow = N_NODES - 1;
    const float4* xrow = (const float4*)(x + (size_t)arow * D);
    float4 af[8];
    #pragma unroll
    for (int kt = 0; kt < 4; ++kt) {
        int fi = kt * 8 + (lane >> 4) * 2;
        af[kt * 2]     = xrow[fi];
        af[kt * 2 + 1] = xrow[fi + 1];
    }

    const float4* W4 = (const float4*)W;
    float4 wreg[8];
    #pragma unroll
    for (int i = 0; i < 8; ++i) wreg[i] = W4[tid + 512 * i];
    #pragma unroll
    for (int i = 0; i < 8; ++i) {
        int idx = tid + 512 * i;
        int k  = idx >> 5;
        int c0 = (idx & 31) * 4;
        float v[4] = {wreg[i].x, wreg[i].y, wreg[i].z, wreg[i].w};
        #pragma unroll
        for (int j = 0; j < 4; ++j) {
            int c = c0 + j;
            int byte = (c * 256 + k * 2) ^ ((c & 7) << 4);
            *(unsigned short*)((char*)wt + byte) = f2bf(v[j]);
        }
    }
    __syncthreads();

    bf16x8 a[4];
    #pragma unroll
    for (int kt = 0; kt < 4; ++kt) {
        float4 u = af[kt * 2], v = af[kt * 2 + 1];
        a[kt][0] = (short)f2bf(u.x); a[kt][1] = (short)f2bf(u.y);
        a[kt][2] = (short)f2bf(u.z); a[kt][3] = (short)f2bf(u.w);
        a[kt][4] = (short)f2bf(v.x); a[kt][5] = (short)f2bf(v.y);
        a[kt][6] = (short)f2bf(v.z); a[kt][7] = (short)f2bf(v.w);
    }

    f32x4 acc[8];
    #pragma unroll
    for (int ct = 0; ct < 8; ++ct) acc[ct] = (f32x4){0.f, 0.f, 0.f, 0.f};

    const int cbase = lane & 15;
    const int kgrp  = (lane >> 4) * 8;
    #pragma unroll
    for (int ct = 0; ct < 8; ++ct) {
        int c = ct * 16 + cbase;
        #pragma unroll
        for (int kt = 0; kt < 4; ++kt) {
            int byte = (c * 256 + (kt * 32 + kgrp) * 2) ^ ((c & 7) << 4);
            bf16x8 bfr = *(const bf16x8*)((const char*)wt + byte);
            acc[ct] = __builtin_amdgcn_mfma_f32_16x16x32_bf16(a[kt], bfr, acc[ct], 0, 0, 0);
        }
    }

    float dq[4]; int orow[4];
    #pragma unroll
    for (int q = 0; q < 4; ++q) {
        orow[q] = rb + (lane >> 4) * 4 + q;
        int rr = orow[q] < N_NODES ? orow[q] : 0;
        dq[q] = rsqrtf((float)deg[rr] + 1.0f);
    }
    #pragma unroll
    for (int ct = 0; ct < 8; ++ct) {
        int col = ct * 16 + (lane & 15);
        #pragma unroll
        for (int q = 0; q < 4; ++q) {
            if (orow[q] < N_NODES)
                h[(size_t)orow[q] * D + col] = f2bf(acc[ct][q] * dq[q]);
        }
    }
}

// ---- K3: fused per-bucket CSR build (in LDS) + gather + epilogue.
// One block per 64-node bucket; 8 groups of 32 lanes gather 8 nodes each.
__global__ __launch_bounds__(256) void bucket_gather(const unsigned int* __restrict__ bins,
                                                     const int* __restrict__ gcursor,
                                                     const ushort4* __restrict__ h4,
                                                     const float4* __restrict__ b4,
                                                     float4* __restrict__ out4) {
    __shared__ int degL[G];
    __shared__ int rsL[G];
    __shared__ int curL[G];
    __shared__ int csrL[CAP];   // 6 KB
    const int b = blockIdx.x, t = threadIdx.x;
    int cb = gcursor[b];
    if (cb > CAP) cb = CAP;
    if (t < G) { degL[t] = 0; curL[t] = 0; }
    __syncthreads();
    const unsigned int* mybins = bins + (size_t)b * CAP;
    for (int i = t; i < cb; i += 256)
        atomicAdd(&degL[(mybins[i] >> 17) & 63], 1);
    __syncthreads();
    if (t < G) {                       // one wave: exclusive scan of 64 degrees
        int v = degL[t];
        int incl = wave_incl_scan(v, t);
        rsL[t] = incl - v;
    }
    __syncthreads();
    for (int i = t; i < cb; i += 256) {
        unsigned int u = mybins[i];
        int dl = (u >> 17) & 63;
        int pos = rsL[dl] + atomicAdd(&curL[dl], 1);
        csrL[pos] = (int)(u & 0x1FFFF);
    }
    __syncthreads();

    const int c = t & 31, g = t >> 5;
    for (int nl = g; nl < G; nl += 8) {
        int node = b * G + nl;
        if (node >= N_NODES) break;    // uniform within group
        int rs = rsL[nl], dg = degL[nl];
        ushort4 hv = h4[(size_t)node * 32 + c];   // self-loop term
        float4 acc = {bf2f(hv.x), bf2f(hv.y), bf2f(hv.z), bf2f(hv.w)};
        int j = 0;
        for (; j + 4 <= dg; j += 4) {             // 4 h-row loads in flight
            int s0 = csrL[rs + j], s1 = csrL[rs + j + 1];
            int s2 = csrL[rs + j + 2], s3 = csrL[rs + j + 3];
            ushort4 v0 = h4[(size_t)s0 * 32 + c];
            ushort4 v1 = h4[(size_t)s1 * 32 + c];
            ushort4 v2 = h4[(size_t)s2 * 32 + c];
            ushort4 v3 = h4[(size_t)s3 * 32 + c];
            acc.x += bf2f(v0.x) + bf2f(v1.x) + bf2f(v2.x) + bf2f(v3.x);
            acc.y += bf2f(v0.y) + bf2f(v1.y) + bf2f(v2.y) + bf2f(v3.y);
            acc.z += bf2f(v0.z) + bf2f(v1.z) + bf2f(v2.z) + bf2f(v3.z);
            acc.w += bf2f(v0.w) + bf2f(v1.w) + bf2f(v2.w) + bf2f(v3.w);
        }
        for (; j < dg; ++j) {
            int s = csrL[rs + j];
            ushort4 v = h4[(size_t)s * 32 + c];
            acc.x += bf2f(v.x); acc.y += bf2f(v.y);
            acc.z += bf2f(v.z); acc.w += bf2f(v.w);
        }
        float dn = rsqrtf((float)dg + 1.0f);
        float4 bb = b4[c];
        float4 o;
        o.x = fmaxf(fmaf(dn, acc.x, bb.x), 0.f);
        o.y = fmaxf(fmaf(dn, acc.y, bb.y), 0.f);
        o.z = fmaxf(fmaf(dn, acc.z, bb.z), 0.f);
        o.w = fmaxf(fmaf(dn, acc.w, bb.w), 0.f);
        out4[(size_t)node * 32 + c] = o;
    }
}

extern "C" void kernel_launch(void* const* d_in, const int* in_sizes, int n_in,
                              void* d_out, int out_size, void* d_ws, size_t ws_size,
                              hipStream_t stream) {
    const float* x  = (const float*)d_in[0];
    // d_in[1] = x_0 (unused by the reference)
    const float* W  = (const float*)d_in[2];
    const float* b  = (const float*)d_in[3];
    const int*   ei = (const int*)d_in[4];   // [2, N_EDGES]: src then dst
    float* out = (float*)d_out;

    // workspace layout (~36 MB)
    unsigned short* h  = (unsigned short*)d_ws;               // N*D bf16 (25.6 MB)
    int*   deg         = (int*)(h + (size_t)N_NODES * D);     // N ints
    int*   gcursor     = deg + N_NODES;                       // NB_PAD ints (adjacent)
    unsigned int* bins = (unsigned int*)(gcursor + NB_PAD);   // NB*CAP (9.6 MB)

    hipMemsetAsync(deg, 0, (N_NODES + NB_PAD) * sizeof(int), stream);  // deg + gcursor

    bin_count<<<(N_EDGES + 256 * EPT - 1) / (256 * EPT), 256, 0, stream>>>(ei, deg, gcursor, bins);
    gemm_h_mfma<<<(N_NODES + 127) / 128, 512, 0, stream>>>(x, W, deg, h);
    bucket_gather<<<NB, 256, 0, stream>>>(bins, gcursor, (const ushort4*)h,
                                          (const float4*)b, (float4*)out);
}

// Round 13
// 283.276 us; speedup vs baseline: 1.0412x; 1.0412x over previous
//
#include <hip/hip_runtime.h>

#define N_NODES 100000
#define N_EDGES 1600000
#define D 128
#define G 256                      // nodes per bin bucket (dst >> 8)
#define NB 391                     // ceil(N_NODES / G)
#define NB_PAD 392
#define CAP 6144                   // bucket capacity: mean 4096, +32 sigma
#define SUBCAP 1536                // 64-node sub-range capacity: mean 1024, +16 sigma
#define EPT 4                      // edges per thread in bin_count

typedef __attribute__((ext_vector_type(8))) short bf16x8;
typedef __attribute__((ext_vector_type(4))) float f32x4;

__device__ inline float bf2f(unsigned short u) {
    return __uint_as_float(((unsigned int)u) << 16);
}
__device__ inline unsigned short f2bf(float f) {  // round-to-nearest-even
    unsigned int u = __float_as_uint(f);
    unsigned int r = u + 0x7FFF + ((u >> 16) & 1);
    return (unsigned short)(r >> 16);
}

__device__ inline int wave_incl_scan(int v, int lane) {
    #pragma unroll
    for (int off = 1; off < 64; off <<= 1) {
        int y = __shfl_up(v, off);
        if (lane >= off) v += y;
    }
    return v;
}

// ---- K1: bin edges by dst>>8, packed (src | dlocal<<17), dlocal 8 bits.
// EPT=4 -> 1563 blocks (6.1/CU) for latency hiding; NO global deg atomics.
__global__ __launch_bounds__(256) void bin_count(const int* __restrict__ ei,
                                                 int* __restrict__ gcursor,
                                                 unsigned int* __restrict__ bins) {
    __shared__ int hist[NB];
    __shared__ int base[NB];
    const int tid = threadIdx.x;
    for (int i = tid; i < NB; i += 256) hist[i] = 0;
    __syncthreads();

    const long long e0 = (long long)blockIdx.x * (256 * EPT) + (long long)tid * EPT;
    const bool active = (e0 < N_EDGES);   // e0 4-aligned, N_EDGES%4==0 -> all-or-nothing
    unsigned int packed[EPT]; int bkt[EPT]; int rnk[EPT];
    if (active) {
        int4 s = *(const int4*)(ei + e0);
        int4 d = *(const int4*)(ei + N_EDGES + e0);
        bkt[0] = d.x >> 8; packed[0] = (unsigned)s.x | ((unsigned)(d.x & 255) << 17);
        bkt[1] = d.y >> 8; packed[1] = (unsigned)s.y | ((unsigned)(d.y & 255) << 17);
        bkt[2] = d.z >> 8; packed[2] = (unsigned)s.z | ((unsigned)(d.z & 255) << 17);
        bkt[3] = d.w >> 8; packed[3] = (unsigned)s.w | ((unsigned)(d.w & 255) << 17);
        #pragma unroll
        for (int j = 0; j < EPT; ++j) rnk[j] = atomicAdd(&hist[bkt[j]], 1);
    }
    __syncthreads();
    for (int i = tid; i < NB; i += 256) {
        int c = hist[i];
        base[i] = c ? atomicAdd(&gcursor[i], c) : 0;
    }
    __syncthreads();
    if (active) {
        #pragma unroll
        for (int j = 0; j < EPT; ++j) {
            int pos = base[bkt[j]] + rnk[j];
            if (pos < CAP) bins[(size_t)bkt[j] * CAP + pos] = packed[j];
        }
    }
}

// ---- K2: per-node degree from sorted bins: LDS histogram + coalesced write.
__global__ __launch_bounds__(256) void deg_bins(const unsigned int* __restrict__ bins,
                                                const int* __restrict__ gcursor,
                                                int* __restrict__ deg) {
    __shared__ int degL[G];
    const int b = blockIdx.x, t = threadIdx.x;
    degL[t] = 0;
    __syncthreads();
    int cb = gcursor[b];
    if (cb > CAP) cb = CAP;
    const unsigned int* mybins = bins + (size_t)b * CAP;
    for (int i = t; i < cb; i += 256)
        atomicAdd(&degL[(mybins[i] >> 17) & 255], 1);
    __syncthreads();
    int node = b * G + t;
    if (node < N_NODES) deg[node] = degL[t];
}

// ---- K3: h'[r] = rsqrt(deg[r]+1) * (x[r] @ W) via bf16 MFMA, stored bf16.
// 512 threads = 8 waves; 128 rows/block. W transposed+XOR-swizzled in LDS.
__global__ __launch_bounds__(512) void gemm_h_mfma(
        const float* __restrict__ x, const float* __restrict__ W,
        const int* __restrict__ deg, unsigned short* __restrict__ h) {
    __shared__ unsigned short wt[D * D];  // 32 KB
    const int tid  = threadIdx.x;
    const int lane = tid & 63;
    const int wv   = tid >> 6;
    const int rb   = blockIdx.x * 128 + wv * 16;

    int arow = rb + (lane & 15);
    if (arow >= N_NODES) arow = N_NODES - 1;
    const float4* xrow = (const float4*)(x + (size_t)arow * D);
    float4 af[8];
    #pragma unroll
    for (int kt = 0; kt < 4; ++kt) {
        int fi = kt * 8 + (lane >> 4) * 2;
        af[kt * 2]     = xrow[fi];
        af[kt * 2 + 1] = xrow[fi + 1];
    }

    const float4* W4 = (const float4*)W;
    float4 wreg[8];
    #pragma unroll
    for (int i = 0; i < 8; ++i) wreg[i] = W4[tid + 512 * i];
    #pragma unroll
    for (int i = 0; i < 8; ++i) {
        int idx = tid + 512 * i;
        int k  = idx >> 5;
        int c0 = (idx & 31) * 4;
        float v[4] = {wreg[i].x, wreg[i].y, wreg[i].z, wreg[i].w};
        #pragma unroll
        for (int j = 0; j < 4; ++j) {
            int c = c0 + j;
            int byte = (c * 256 + k * 2) ^ ((c & 7) << 4);
            *(unsigned short*)((char*)wt + byte) = f2bf(v[j]);
        }
    }
    __syncthreads();

    bf16x8 a[4];
    #pragma unroll
    for (int kt = 0; kt < 4; ++kt) {
        float4 u = af[kt * 2], v = af[kt * 2 + 1];
        a[kt][0] = (short)f2bf(u.x); a[kt][1] = (short)f2bf(u.y);
        a[kt][2] = (short)f2bf(u.z); a[kt][3] = (short)f2bf(u.w);
        a[kt][4] = (short)f2bf(v.x); a[kt][5] = (short)f2bf(v.y);
        a[kt][6] = (short)f2bf(v.z); a[kt][7] = (short)f2bf(v.w);
    }

    f32x4 acc[8];
    #pragma unroll
    for (int ct = 0; ct < 8; ++ct) acc[ct] = (f32x4){0.f, 0.f, 0.f, 0.f};

    const int cbase = lane & 15;
    const int kgrp  = (lane >> 4) * 8;
    #pragma unroll
    for (int ct = 0; ct < 8; ++ct) {
        int c = ct * 16 + cbase;
        #pragma unroll
        for (int kt = 0; kt < 4; ++kt) {
            int byte = (c * 256 + (kt * 32 + kgrp) * 2) ^ ((c & 7) << 4);
            bf16x8 bfr = *(const bf16x8*)((const char*)wt + byte);
            acc[ct] = __builtin_amdgcn_mfma_f32_16x16x32_bf16(a[kt], bfr, acc[ct], 0, 0, 0);
        }
    }

    float dq[4]; int orow[4];
    #pragma unroll
    for (int q = 0; q < 4; ++q) {
        orow[q] = rb + (lane >> 4) * 4 + q;
        int rr = orow[q] < N_NODES ? orow[q] : 0;
        dq[q] = rsqrtf((float)deg[rr] + 1.0f);
    }
    #pragma unroll
    for (int ct = 0; ct < 8; ++ct) {
        int col = ct * 16 + (lane & 15);
        #pragma unroll
        for (int q = 0; q < 4; ++q) {
            if (orow[q] < N_NODES)
                h[(size_t)orow[q] * D + col] = f2bf(acc[ct][q] * dq[q]);
        }
    }
}

// ---- K4: fused sub-bucket CSR build (in LDS) + gather + epilogue.
// Block j serves nodes [j*64, j*64+64): reads bucket j>>2's bins, filters
// to sub-range j&3. 1563 blocks keep gather TLP high.
__global__ __launch_bounds__(256) void bucket_gather(const unsigned int* __restrict__ bins,
                                                     const int* __restrict__ gcursor,
                                                     const ushort4* __restrict__ h4,
                                                     const float4* __restrict__ b4,
                                                     float4* __restrict__ out4) {
    __shared__ int degL[64];
    __shared__ int rsL[64];
    __shared__ int curL[64];
    __shared__ int csrL[SUBCAP];   // 6 KB
    const int j = blockIdx.x, t = threadIdx.x;
    const int b = j >> 2, q = j & 3;
    int cb = gcursor[b];
    if (cb > CAP) cb = CAP;
    if (t < 64) { degL[t] = 0; curL[t] = 0; }
    __syncthreads();
    const unsigned int* mybins = bins + (size_t)b * CAP;
    for (int i = t; i < cb; i += 256) {
        unsigned int u = mybins[i];
        if (((u >> 23) & 3) == (unsigned)q)
            atomicAdd(&degL[(u >> 17) & 63], 1);
    }
    __syncthreads();
    if (t < 64) {                  // wave 0: exclusive scan of 64 degrees
        int v = degL[t];
        int incl = wave_incl_scan(v, t);
        rsL[t] = incl - v;
    }
    __syncthreads();
    for (int i = t; i < cb; i += 256) {
        unsigned int u = mybins[i];
        if (((u >> 23) & 3) == (unsigned)q) {
            int dl = (u >> 17) & 63;
            int pos = rsL[dl] + atomicAdd(&curL[dl], 1);
            if (pos < SUBCAP) csrL[pos] = (int)(u & 0x1FFFF);
        }
    }
    __syncthreads();

    const int c = t & 31, g = t >> 5;
    for (int nl = g; nl < 64; nl += 8) {
        int node = j * 64 + nl;
        if (node >= N_NODES) break;    // uniform within lane-group
        int rs = rsL[nl], dg = degL[nl];
        ushort4 hv = h4[(size_t)node * 32 + c];   // self-loop term
        float4 acc = {bf2f(hv.x), bf2f(hv.y), bf2f(hv.z), bf2f(hv.w)};
        int jj = 0;
        for (; jj + 4 <= dg; jj += 4) {           // 4 h-row loads in flight
            int s0 = csrL[rs + jj],     s1 = csrL[rs + jj + 1];
            int s2 = csrL[rs + jj + 2], s3 = csrL[rs + jj + 3];
            ushort4 v0 = h4[(size_t)s0 * 32 + c];
            ushort4 v1 = h4[(size_t)s1 * 32 + c];
            ushort4 v2 = h4[(size_t)s2 * 32 + c];
            ushort4 v3 = h4[(size_t)s3 * 32 + c];
            acc.x += bf2f(v0.x) + bf2f(v1.x) + bf2f(v2.x) + bf2f(v3.x);
            acc.y += bf2f(v0.y) + bf2f(v1.y) + bf2f(v2.y) + bf2f(v3.y);
            acc.z += bf2f(v0.z) + bf2f(v1.z) + bf2f(v2.z) + bf2f(v3.z);
            acc.w += bf2f(v0.w) + bf2f(v1.w) + bf2f(v2.w) + bf2f(v3.w);
        }
        for (; jj < dg; ++jj) {
            int s = csrL[rs + jj];
            ushort4 v = h4[(size_t)s * 32 + c];
            acc.x += bf2f(v.x); acc.y += bf2f(v.y);
            acc.z += bf2f(v.z); acc.w += bf2f(v.w);
        }
        float dn = rsqrtf((float)dg + 1.0f);
        float4 bb = b4[c];
        float4 o;
        o.x = fmaxf(fmaf(dn, acc.x, bb.x), 0.f);
        o.y = fmaxf(fmaf(dn, acc.y, bb.y), 0.f);
        o.z = fmaxf(fmaf(dn, acc.z, bb.z), 0.f);
        o.w = fmaxf(fmaf(dn, acc.w, bb.w), 0.f);
        out4[(size_t)node * 32 + c] = o;
    }
}

extern "C" void kernel_launch(void* const* d_in, const int* in_sizes, int n_in,
                              void* d_out, int out_size, void* d_ws, size_t ws_size,
                              hipStream_t stream) {
    const float* x  = (const float*)d_in[0];
    // d_in[1] = x_0 (unused by the reference)
    const float* W  = (const float*)d_in[2];
    const float* b  = (const float*)d_in[3];
    const int*   ei = (const int*)d_in[4];   // [2, N_EDGES]: src then dst
    float* out = (float*)d_out;

    // workspace layout (~36 MB)
    unsigned short* h  = (unsigned short*)d_ws;               // N*D bf16 (25.6 MB)
    int*   deg         = (int*)(h + (size_t)N_NODES * D);     // N ints
    int*   gcursor     = deg + N_NODES;                       // NB_PAD ints
    unsigned int* bins = (unsigned int*)(gcursor + NB_PAD);   // NB*CAP (9.6 MB)

    hipMemsetAsync(gcursor, 0, NB_PAD * sizeof(int), stream);

    bin_count<<<(N_EDGES + 256 * EPT - 1) / (256 * EPT), 256, 0, stream>>>(ei, gcursor, bins);
    deg_bins<<<NB, 256, 0, stream>>>(bins, gcursor, deg);
    gemm_h_mfma<<<(N_NODES + 127) / 128, 512, 0, stream>>>(x, W, deg, h);
    bucket_gather<<<NB * 4, 256, 0, stream>>>(bins, gcursor, (const ushort4*)h,
                                              (const float4*)b, (float4*)out);
}

// Round 16
// 278.097 us; speedup vs baseline: 1.0606x; 1.0186x over previous
//
#include <hip/hip_runtime.h>

#define N_NODES 100000
#define N_EDGES 1600000
#define D 128
#define G 256                      // nodes per bin bucket (dst >> 8)
#define NB 391                     // ceil(N_NODES / G)
#define NB_PAD 392
#define CAP 8192                   // bucket capacity incl. ~59% pad holes (mean used ~6500)
#define SUBCAP 768                 // 32-node sub-range capacity: mean 512, +11 sigma
#define EPT 16                     // edges per thread in bin_count
#define SENT 0xFFFFFFFFu

typedef __attribute__((ext_vector_type(8))) short bf16x8;
typedef __attribute__((ext_vector_type(4))) float f32x4;

__device__ inline float bf2f(unsigned short u) {
    return __uint_as_float(((unsigned int)u) << 16);
}
__device__ inline unsigned short f2bf(float f) {  // round-to-nearest-even
    unsigned int u = __float_as_uint(f);
    unsigned int r = u + 0x7FFF + ((u >> 16) & 1);
    return (unsigned short)(r >> 16);
}

__device__ inline int wave_incl_scan(int v, int lane) {
    #pragma unroll
    for (int off = 1; off < 64; off <<= 1) {
        int y = __shfl_up(v, off);
        if (lane >= off) v += y;
    }
    return v;
}

// ---- K1: bin edges by dst>>8, packed (src | dlocal<<17).
// Per-(block,bucket) reservations rounded up to 16 slots (64 B) so runs are
// line-aligned and lines are never shared across blocks (single writeback).
// Unused slots keep the 0xFFFFFFFF sentinel from the pre-memset.
__global__ __launch_bounds__(256) void bin_count(const int* __restrict__ ei,
                                                 int* __restrict__ gcursor,
                                                 unsigned int* __restrict__ bins) {
    __shared__ int hist[NB];
    __shared__ int base[NB];
    const int tid = threadIdx.x;
    for (int i = tid; i < NB; i += 256) hist[i] = 0;
    __syncthreads();

    const long long e0 = (long long)blockIdx.x * (256 * EPT) + (long long)tid * EPT;
    const bool active = (e0 < N_EDGES);   // tail is EPT-aligned -> all-or-nothing
    unsigned int packed[EPT]; int bkt[EPT]; int rnk[EPT];
    if (active) {
        const int4* s4 = (const int4*)(ei + e0);
        const int4* d4 = (const int4*)(ei + N_EDGES + e0);
        #pragma unroll
        for (int q = 0; q < EPT / 4; ++q) {
            int4 s = s4[q], d = d4[q];
            int j = q * 4;
            bkt[j+0] = d.x >> 8; packed[j+0] = (unsigned)s.x | ((unsigned)(d.x & 255) << 17);
            bkt[j+1] = d.y >> 8; packed[j+1] = (unsigned)s.y | ((unsigned)(d.y & 255) << 17);
            bkt[j+2] = d.z >> 8; packed[j+2] = (unsigned)s.z | ((unsigned)(d.z & 255) << 17);
            bkt[j+3] = d.w >> 8; packed[j+3] = (unsigned)s.w | ((unsigned)(d.w & 255) << 17);
        }
        #pragma unroll
        for (int j = 0; j < EPT; ++j) rnk[j] = atomicAdd(&hist[bkt[j]], 1);
    }
    __syncthreads();
    for (int i = tid; i < NB; i += 256) {
        int c = hist[i];
        int cpad = (c + 15) & ~15;            // 64 B-aligned reservation
        base[i] = cpad ? atomicAdd(&gcursor[i], cpad) : 0;
    }
    __syncthreads();
    if (active) {
        #pragma unroll
        for (int j = 0; j < EPT; ++j) {
            int pos = base[bkt[j]] + rnk[j];
            if (pos < CAP) bins[(size_t)bkt[j] * CAP + pos] = packed[j];
        }
    }
}

// ---- K2: per-node degree from binned edges (sentinel-skipping histogram).
__global__ __launch_bounds__(256) void deg_bins(const unsigned int* __restrict__ bins,
                                                const int* __restrict__ gcursor,
                                                int* __restrict__ deg) {
    __shared__ int degL[G];
    const int b = blockIdx.x, t = threadIdx.x;
    degL[t] = 0;
    __syncthreads();
    int cb = gcursor[b];
    if (cb > CAP) cb = CAP;
    const unsigned int* mybins = bins + (size_t)b * CAP;
    for (int i = t; i < cb; i += 256) {
        unsigned int u = mybins[i];
        if (u != SENT) atomicAdd(&degL[(u >> 17) & 255], 1);
    }
    __syncthreads();
    int node = b * G + t;
    if (node < N_NODES) deg[node] = degL[t];
}

// ---- K3: h'[r] = rsqrt(deg[r]+1) * (x[r] @ W) via bf16 MFMA, stored bf16.
// 512 threads = 8 waves; 128 rows/block. W transposed+XOR-swizzled in LDS.
__global__ __launch_bounds__(512) void gemm_h_mfma(
        const float* __restrict__ x, const float* __restrict__ W,
        const int* __restrict__ deg, unsigned short* __restrict__ h) {
    __shared__ unsigned short wt[D * D];  // 32 KB
    const int tid  = threadIdx.x;
    const int lane = tid & 63;
    const int wv   = tid >> 6;
    const int rb   = blockIdx.x * 128 + wv * 16;

    int arow = rb + (lane & 15);
    if (arow >= N_NODES) arow = N_NODES - 1;
    const float4* xrow = (const float4*)(x + (size_t)arow * D);
    float4 af[8];
    #pragma unroll
    for (int kt = 0; kt < 4; ++kt) {
        int fi = kt * 8 + (lane >> 4) * 2;
        af[kt * 2]     = xrow[fi];
        af[kt * 2 + 1] = xrow[fi + 1];
    }

    const float4* W4 = (const float4*)W;
    float4 wreg[8];
    #pragma unroll
    for (int i = 0; i < 8; ++i) wreg[i] = W4[tid + 512 * i];
    #pragma unroll
    for (int i = 0; i < 8; ++i) {
        int idx = tid + 512 * i;
        int k  = idx >> 5;
        int c0 = (idx & 31) * 4;
        float v[4] = {wreg[i].x, wreg[i].y, wreg[i].z, wreg[i].w};
        #pragma unroll
        for (int j = 0; j < 4; ++j) {
            int c = c0 + j;
            int byte = (c * 256 + k * 2) ^ ((c & 7) << 4);
            *(unsigned short*)((char*)wt + byte) = f2bf(v[j]);
        }
    }
    __syncthreads();

    bf16x8 a[4];
    #pragma unroll
    for (int kt = 0; kt < 4; ++kt) {
        float4 u = af[kt * 2], v = af[kt * 2 + 1];
        a[kt][0] = (short)f2bf(u.x); a[kt][1] = (short)f2bf(u.y);
        a[kt][2] = (short)f2bf(u.z); a[kt][3] = (short)f2bf(u.w);
        a[kt][4] = (short)f2bf(v.x); a[kt][5] = (short)f2bf(v.y);
        a[kt][6] = (short)f2bf(v.z); a[kt][7] = (short)f2bf(v.w);
    }

    f32x4 acc[8];
    #pragma unroll
    for (int ct = 0; ct < 8; ++ct) acc[ct] = (f32x4){0.f, 0.f, 0.f, 0.f};

    const int cbase = lane & 15;
    const int kgrp  = (lane >> 4) * 8;
    #pragma unroll
    for (int ct = 0; ct < 8; ++ct) {
        int c = ct * 16 + cbase;
        #pragma unroll
        for (int kt = 0; kt < 4; ++kt) {
            int byte = (c * 256 + (kt * 32 + kgrp) * 2) ^ ((c & 7) << 4);
            bf16x8 bfr = *(const bf16x8*)((const char*)wt + byte);
            acc[ct] = __builtin_amdgcn_mfma_f32_16x16x32_bf16(a[kt], bfr, acc[ct], 0, 0, 0);
        }
    }

    float dq[4]; int orow[4];
    #pragma unroll
    for (int q = 0; q < 4; ++q) {
        orow[q] = rb + (lane >> 4) * 4 + q;
        int rr = orow[q] < N_NODES ? orow[q] : 0;
        dq[q] = rsqrtf((float)deg[rr] + 1.0f);
    }
    #pragma unroll
    for (int ct = 0; ct < 8; ++ct) {
        int col = ct * 16 + (lane & 15);
        #pragma unroll
        for (int q = 0; q < 4; ++q) {
            if (orow[q] < N_NODES)
                h[(size_t)orow[q] * D + col] = f2bf(acc[ct][q] * dq[q]);
        }
    }
}

// ---- K4: fused sub-bucket CSR build (in LDS) + gather + epilogue.
// Block j serves 32 nodes: bucket j>>3, sub-range j&7. 3128 blocks for TLP.
__global__ __launch_bounds__(256) void bucket_gather(const unsigned int* __restrict__ bins,
                                                     const int* __restrict__ gcursor,
                                                     const ushort4* __restrict__ h4,
                                                     const float4* __restrict__ b4,
                                                     float4* __restrict__ out4) {
    __shared__ int degL[32];
    __shared__ int rsL[32];
    __shared__ int curL[32];
    __shared__ int csrL[SUBCAP];   // 3 KB
    const int j = blockIdx.x, t = threadIdx.x;
    const int b = j >> 3;
    const unsigned int q = (unsigned)(j & 7);
    int cb = gcursor[b];
    if (cb > CAP) cb = CAP;
    if (t < 32) { degL[t] = 0; curL[t] = 0; }
    __syncthreads();
    const unsigned int* mybins = bins + (size_t)b * CAP;
    for (int i = t; i < cb; i += 256) {
        unsigned int u = mybins[i];
        if (u != SENT && ((u >> 22) & 7) == q)
            atomicAdd(&degL[(u >> 17) & 31], 1);
    }
    __syncthreads();
    if (t < 32) {                  // lanes 0-31 of wave 0: exclusive scan
        int v = degL[t];
        int incl = wave_incl_scan(v, t);
        rsL[t] = incl - v;
    }
    __syncthreads();
    for (int i = t; i < cb; i += 256) {
        unsigned int u = mybins[i];
        if (u != SENT && ((u >> 22) & 7) == q) {
            int dl = (u >> 17) & 31;
            int pos = rsL[dl] + atomicAdd(&curL[dl], 1);
            if (pos < SUBCAP) csrL[pos] = (int)(u & 0x1FFFF);
        }
    }
    __syncthreads();

    const int c = t & 31, g = t >> 5;
    for (int nl = g; nl < 32; nl += 8) {
        int node = b * G + (int)q * 32 + nl;
        if (node >= N_NODES) break;    // uniform within lane-group
        int rs = rsL[nl], dg = degL[nl];
        ushort4 hv = h4[(size_t)node * 32 + c];   // self-loop term
        float4 acc = {bf2f(hv.x), bf2f(hv.y), bf2f(hv.z), bf2f(hv.w)};
        int jj = 0;
        for (; jj + 4 <= dg; jj += 4) {           // 4 h-row loads in flight
            int s0 = csrL[rs + jj],     s1 = csrL[rs + jj + 1];
            int s2 = csrL[rs + jj + 2], s3 = csrL[rs + jj + 3];
            ushort4 v0 = h4[(size_t)s0 * 32 + c];
            ushort4 v1 = h4[(size_t)s1 * 32 + c];
            ushort4 v2 = h4[(size_t)s2 * 32 + c];
            ushort4 v3 = h4[(size_t)s3 * 32 + c];
            acc.x += bf2f(v0.x) + bf2f(v1.x) + bf2f(v2.x) + bf2f(v3.x);
            acc.y += bf2f(v0.y) + bf2f(v1.y) + bf2f(v2.y) + bf2f(v3.y);
            acc.z += bf2f(v0.z) + bf2f(v1.z) + bf2f(v2.z) + bf2f(v3.z);
            acc.w += bf2f(v0.w) + bf2f(v1.w) + bf2f(v2.w) + bf2f(v3.w);
        }
        for (; jj < dg; ++jj) {
            int s = csrL[rs + jj];
            ushort4 v = h4[(size_t)s * 32 + c];
            acc.x += bf2f(v.x); acc.y += bf2f(v.y);
            acc.z += bf2f(v.z); acc.w += bf2f(v.w);
        }
        float dn = rsqrtf((float)dg + 1.0f);
        float4 bb = b4[c];
        float4 o;
        o.x = fmaxf(fmaf(dn, acc.x, bb.x), 0.f);
        o.y = fmaxf(fmaf(dn, acc.y, bb.y), 0.f);
        o.z = fmaxf(fmaf(dn, acc.z, bb.z), 0.f);
        o.w = fmaxf(fmaf(dn, acc.w, bb.w), 0.f);
        out4[(size_t)node * 32 + c] = o;
    }
}

extern "C" void kernel_launch(void* const* d_in, const int* in_sizes, int n_in,
                              void* d_out, int out_size, void* d_ws, size_t ws_size,
                              hipStream_t stream) {
    const float* x  = (const float*)d_in[0];
    // d_in[1] = x_0 (unused by the reference)
    const float* W  = (const float*)d_in[2];
    const float* b  = (const float*)d_in[3];
    const int*   ei = (const int*)d_in[4];   // [2, N_EDGES]: src then dst
    float* out = (float*)d_out;

    // workspace layout (~39 MB)
    unsigned short* h  = (unsigned short*)d_ws;               // N*D bf16 (25.6 MB)
    int*   deg         = (int*)(h + (size_t)N_NODES * D);     // N ints
    int*   gcursor     = deg + N_NODES;                       // NB_PAD ints
    unsigned int* bins = (unsigned int*)(gcursor + NB_PAD);   // NB*CAP (12.8 MB)

    hipMemsetAsync(gcursor, 0, NB_PAD * sizeof(int), stream);
    hipMemsetAsync(bins, 0xFF, (size_t)NB * CAP * sizeof(unsigned int), stream);

    bin_count<<<(N_EDGES + 256 * EPT - 1) / (256 * EPT), 256, 0, stream>>>(ei, gcursor, bins);
    deg_bins<<<NB, 256, 0, stream>>>(bins, gcursor, deg);
    gemm_h_mfma<<<(N_NODES + 127) / 128, 512, 0, stream>>>(x, W, deg, h);
    bucket_gather<<<NB * 8, 256, 0, stream>>>(bins, gcursor, (const ushort4*)h,
                                              (const float4*)b, (float4*)out);
}